// Round 4
// baseline (81.010 us; speedup 1.0000x reference)
//
#include <hip/hip_runtime.h>

// ---------------------------------------------------------------------------
// y = x @ Q^T where Q = H_0 H_1 ... H_{N-1}, H_n = I - 2 v_n v_n^T/(v_n.v_n+eps)
// S=256, N=258, B=65536.
// Phase 1: c2[n] = 2/(v_n.v_n + 1e-16)
// Phase 2: Q rows (independent chains), 16 lanes/row, DPP-only reduce
// Phase 3: GEMM y[b][j] = sum_k x[b][k] Q[j][k]  (BT layout, bf16 MFMA)
// ---------------------------------------------------------------------------

#define GLOAD_LDS16(g, l)                                                      \
  __builtin_amdgcn_global_load_lds(                                            \
      (const __attribute__((address_space(1))) void*)(g),                      \
      (__attribute__((address_space(3))) void*)(l), 16, 0, 0)

typedef __attribute__((ext_vector_type(8))) short bf16x8;
typedef __attribute__((ext_vector_type(4))) float f32x4;

__device__ __forceinline__ unsigned short f2bf_rne(float f) {
  unsigned u = __builtin_bit_cast(unsigned, f);
  return (unsigned short)((u + 0x7fffu + ((u >> 16) & 1u)) >> 16);
}

// DPP-shuffled add: v + dpp(v). CTRL: 0xB1=quad xor1, 0x4E=quad xor2,
// 0x124=row_ror:4, 0x128=row_ror:8. Pure VALU latency, no LDS.
template <int CTRL>
__device__ __forceinline__ float dpp_add(float v) {
  int t = __builtin_amdgcn_update_dpp(0, __builtin_bit_cast(int, v), CTRL, 0xF,
                                      0xF, true);
  return v + __builtin_bit_cast(float, t);
}

// ---------------- Phase 1: inner products -> c2 ----------------------------
__global__ void hh_inner(const float* __restrict__ vecs, float* __restrict__ c2) {
  const int n = blockIdx.x;   // 0..257
  const int l = threadIdx.x;  // 0..63
  const float* v = vecs + n * 256;
  float p = 0.f;
#pragma unroll
  for (int i = 0; i < 4; ++i) {
    float t = v[l + 64 * i];
    p += t * t;
  }
#pragma unroll
  for (int off = 32; off; off >>= 1) p += __shfl_xor(p, off);
  if (l == 0) c2[n] = 2.0f / (p + 1e-16f);
}

// ---------------- Phase 2: Q rows ------------------------------------------
// 64 blocks x 64 threads (1 wave). Lane l: row-in-block r=l>>4, col c=l&15.
// Each lane owns 16 contiguous columns of one Q row. The per-step dot-reduce
// stays inside a 16-lane DPP row (quad_perm + row_ror) -> no LDS ops on the
// critical chain. v is prefetched 4 steps deep (A0/A1/B0/B1 reg buffers).
// __launch_bounds__(64,1): latency-bound 1-wave kernel -> give regalloc the
// full VGPR budget so the 4x16-float prefetch buffers do NOT spill (R3 had
// VGPR_Count=56 -> scratch spill -> 437 cy/step).
__launch_bounds__(64, 1)
__global__ void hh_qrows(const float* __restrict__ vecs,
                         const float* __restrict__ c2,
                         unsigned short* __restrict__ Qb) {
  const int l = threadIdx.x;
  const int r = l >> 4;
  const int c = l & 15;
  const int row = blockIdx.x * 4 + r;
  const int col0 = c * 16;

  float q[16];
#pragma unroll
  for (int i = 0; i < 16; ++i) q[i] = (col0 + i == row) ? 1.f : 0.f;

  auto load16 = [&](float(&d)[16], int n) {
    const float4* v = (const float4*)(vecs + (long)n * 256 + col0);
#pragma unroll
    for (int i = 0; i < 4; ++i) {
      float4 t = v[i];
      d[4 * i] = t.x; d[4 * i + 1] = t.y; d[4 * i + 2] = t.z; d[4 * i + 3] = t.w;
    }
  };

  auto step = [&](const float(&a)[16], float cc) {
    float p0 = 0.f, p1 = 0.f, p2 = 0.f, p3 = 0.f;
#pragma unroll
    for (int i = 0; i < 4; ++i) {
      p0 = fmaf(q[i], a[i], p0);
      p1 = fmaf(q[4 + i], a[4 + i], p1);
      p2 = fmaf(q[8 + i], a[8 + i], p2);
      p3 = fmaf(q[12 + i], a[12 + i], p3);
    }
    float p = (p0 + p1) + (p2 + p3);
    p = dpp_add<0xB1>(p);   // xor1 within quad
    p = dpp_add<0x4E>(p);   // xor2 within quad
    p = dpp_add<0x124>(p);  // row_ror:4  (quad-sum rotate)
    p = dpp_add<0x128>(p);  // row_ror:8  -> full 16-lane sum in all lanes
    const float s = cc * p;
#pragma unroll
    for (int i = 0; i < 16; ++i) q[i] = fmaf(-s, a[i], q[i]);
  };

  float A0[16], A1[16], B0[16], B1[16];
  load16(A0, 0); load16(A1, 1); load16(B0, 2); load16(B1, 3);
  float cA0 = c2[0], cA1 = c2[1], cB0 = c2[2], cB1 = c2[3];

  for (int t = 0; t < 64; ++t) {
    const int s4 = 4 * t;
    step(A0, cA0);
    step(A1, cA1);
    const int n0 = min(s4 + 4, 257), n1 = min(s4 + 5, 257);
    load16(A0, n0); load16(A1, n1);
    cA0 = c2[n0]; cA1 = c2[n1];
    step(B0, cB0);
    step(B1, cB1);
    const int n2 = min(s4 + 6, 257), n3 = min(s4 + 7, 257);
    load16(B0, n2); load16(B1, n3);
    cB0 = c2[n2]; cB1 = c2[n3];
  }
  step(A0, cA0);  // step 256
  step(A1, cA1);  // step 257

#pragma unroll
  for (int i = 0; i < 16; ++i) Qb[row * 256 + col0 + i] = f2bf_rne(q[i]);
}

// ---------------- Phase 3: GEMM --------------------------------------------
// C[M=65536][256] = A[M][K=256](f32, cvt->bf16) * B[N=256][K=256](bf16, BT)
// Block: BM=128, BN=256 (full N -> x read exactly once), BK=32, 512 thr (8 waves).
// Wave grid 2x4; per-wave 64x64 = 4x4 frags of 16x16x32.
// LDS 64KB: A dbuf [128][32] f32 @0/16K, B dbuf [256][32] bf16 @32K/48K.
// XOR-swizzled staging (swizzle applied to the GLOBAL source address, LDS dest
// linear as required by global_load_lds) to avoid bank conflicts on ds_read.
__launch_bounds__(512)
__global__ void hh_gemm(const float* __restrict__ X,
                        const unsigned short* __restrict__ Qb,
                        float* __restrict__ Y) {
  __shared__ __align__(128) char lds[65536];
  const int tid = threadIdx.x;
  const int lane = tid & 63;
  const int wid = tid >> 6;
  const int wm = wid >> 2;  // 0..1
  const int wn = wid & 3;   // 0..3
  const int fr = lane & 15; // fragment row (A-row / B-col)
  const int fg = lane >> 4; // k-group
  const long bm0 = (long)blockIdx.x * 128;

  auto stage = [&](int buf, int kt) {
    // A tile [128][32] f32: 8 segs of 16B per row; phys seg = seg ^ (row&7)
#pragma unroll
    for (int r2 = 0; r2 < 2; ++r2) {
      int slot = r2 * 512 + tid;
      int row = slot >> 3, seg = slot & 7;
      int ps = seg ^ (row & 7);
      GLOAD_LDS16(X + (bm0 + row) * 256 + kt * 32 + ps * 4,
                  lds + buf * 16384 + slot * 16);
    }
    // B tile [256][32] bf16: 4 segs of 16B per row; phys seg = seg ^ (row&3)
#pragma unroll
    for (int r2 = 0; r2 < 2; ++r2) {
      int slot = r2 * 512 + tid;
      int row = slot >> 2, seg = slot & 3;
      int ps = seg ^ (row & 3);
      GLOAD_LDS16(Qb + row * 256 + kt * 32 + ps * 8,
                  lds + 32768 + buf * 16384 + slot * 16);
    }
  };

  f32x4 acc[4][4];
#pragma unroll
  for (int m = 0; m < 4; ++m)
#pragma unroll
    for (int n = 0; n < 4; ++n) acc[m][n] = (f32x4){0.f, 0.f, 0.f, 0.f};

  stage(0, 0);
  __syncthreads();

  for (int kt = 0; kt < 8; ++kt) {
    const int cur = kt & 1;
    if (kt < 7) stage(cur ^ 1, kt + 1);

    bf16x8 aF[4], bF[4];
#pragma unroll
    for (int m = 0; m < 4; ++m) {
      int row = wm * 64 + m * 16 + fr;  // 0..127
      int s0 = (2 * fg) ^ (row & 7);
      int s1 = (2 * fg + 1) ^ (row & 7);
      const f32x4 x0 = *(const f32x4*)(lds + cur * 16384 + row * 128 + s0 * 16);
      const f32x4 x1 = *(const f32x4*)(lds + cur * 16384 + row * 128 + s1 * 16);
      bf16x8 t;
      t[0] = (short)f2bf_rne(x0[0]);
      t[1] = (short)f2bf_rne(x0[1]);
      t[2] = (short)f2bf_rne(x0[2]);
      t[3] = (short)f2bf_rne(x0[3]);
      t[4] = (short)f2bf_rne(x1[0]);
      t[5] = (short)f2bf_rne(x1[1]);
      t[6] = (short)f2bf_rne(x1[2]);
      t[7] = (short)f2bf_rne(x1[3]);
      aF[m] = t;
    }
#pragma unroll
    for (int n = 0; n < 4; ++n) {
      int row = wn * 64 + n * 16 + fr;  // 0..255
      int ps = fg ^ (row & 3);
      bF[n] = *(const bf16x8*)(lds + 32768 + cur * 16384 + row * 64 + ps * 16);
    }
#pragma unroll
    for (int m = 0; m < 4; ++m)
#pragma unroll
      for (int n = 0; n < 4; ++n)
        acc[m][n] =
            __builtin_amdgcn_mfma_f32_16x16x32_bf16(aF[m], bF[n], acc[m][n], 0, 0, 0);
    __syncthreads();
  }

  // Epilogue: C/D layout col = lane&15, row = (lane>>4)*4 + reg
#pragma unroll
  for (int m = 0; m < 4; ++m)
#pragma unroll
    for (int n = 0; n < 4; ++n)
#pragma unroll
      for (int r = 0; r < 4; ++r) {
        long grow = bm0 + wm * 64 + m * 16 + fg * 4 + r;
        int gcol = wn * 64 + n * 16 + fr;
        Y[grow * 256 + gcol] = acc[m][n][r];
      }
}

// ---------------------------------------------------------------------------
extern "C" void kernel_launch(void* const* d_in, const int* in_sizes, int n_in,
                              void* d_out, int out_size, void* d_ws, size_t ws_size,
                              hipStream_t stream) {
  const float* x = (const float*)d_in[0];      // [65536][256] f32
  const float* vecs = (const float*)d_in[1];   // [258][256] f32
  float* y = (float*)d_out;                    // [65536][256] f32

  float* c2 = (float*)d_ws;                                    // 258 f32
  unsigned short* Qb = (unsigned short*)((char*)d_ws + 4096);  // 256x256 bf16

  hh_inner<<<258, 64, 0, stream>>>(vecs, c2);
  hh_qrows<<<64, 64, 0, stream>>>(vecs, c2, Qb);
  hh_gemm<<<512, 512, 0, stream>>>(x, Qb, y);
}

// Round 5
// 66.306 us; speedup vs baseline: 1.2218x; 1.2218x over previous
//
#include <hip/hip_runtime.h>

// ---------------------------------------------------------------------------
// y = x @ Q^T where Q = H_0 H_1 ... H_{N-1}, H_n = I - 2 v_n v_n^T/(v_n.v_n+eps)
// S=256, N=258, B=65536.
// Phase 1: u_n = sqrt(2/(v_n.v_n+eps)) * v_n  (rows 258..271 zeroed: no-op pad)
// Phase 2: Q rows: q -= (q.u_n) u_n, 258 steps; 16 lanes/row, DPP reduce,
//          depth-8 inline-asm load pipeline (compiler sinks C++ prefetch).
// Phase 3: GEMM y[b][j] = sum_k x[b][k] Q[j][k]  (BT layout, bf16 MFMA)
// ---------------------------------------------------------------------------

#define GLOAD_LDS16(g, l)                                                      \
  __builtin_amdgcn_global_load_lds(                                            \
      (const __attribute__((address_space(1))) void*)(g),                      \
      (__attribute__((address_space(3))) void*)(l), 16, 0, 0)

typedef __attribute__((ext_vector_type(8))) short bf16x8;
typedef __attribute__((ext_vector_type(4))) float f32x4;

__device__ __forceinline__ unsigned short f2bf_rne(float f) {
  unsigned u = __builtin_bit_cast(unsigned, f);
  return (unsigned short)((u + 0x7fffu + ((u >> 16) & 1u)) >> 16);
}

// DPP-shuffled add: v + dpp(v). CTRL: 0xB1=quad xor1, 0x4E=quad xor2,
// 0x124=row_ror:4, 0x128=row_ror:8. Pure VALU latency, no LDS.
template <int CTRL>
__device__ __forceinline__ float dpp_add(float v) {
  int t = __builtin_amdgcn_update_dpp(0, __builtin_bit_cast(int, v), CTRL, 0xF,
                                      0xF, true);
  return v + __builtin_bit_cast(float, t);
}

// ---------------- Phase 1: scaled vectors u --------------------------------
// 272 blocks x 64 lanes. Lane l owns 4 contiguous floats (float4 at l*16B).
// n<258: u_n = v_n * sqrt(2/(v.v+1e-16)); n>=258: zeros (pipeline pad rows).
__global__ void hh_scale(const float* __restrict__ vecs, float* __restrict__ u) {
  const int n = blockIdx.x;   // 0..271
  const int l = threadIdx.x;  // 0..63
  float4* uo = (float4*)(u + (long)n * 256) + l;
  if (n >= 258) {
    *uo = make_float4(0.f, 0.f, 0.f, 0.f);
    return;
  }
  const float4 v = *((const float4*)(vecs + (long)n * 256) + l);
  float p = v.x * v.x + v.y * v.y + v.z * v.z + v.w * v.w;
#pragma unroll
  for (int off = 32; off; off >>= 1) p += __shfl_xor(p, off);
  const float s = sqrtf(2.0f / (p + 1e-16f));
  *uo = make_float4(v.x * s, v.y * s, v.z * s, v.w * s);
}

// ---------------- Phase 2: Q rows ------------------------------------------
// 64 blocks x 64 threads (1 wave). Lane l: row-in-block r=l>>4, col c=l&15.
// Each lane owns 16 contiguous columns of one Q row. Per-step dot-reduce
// stays inside a 16-lane DPP row. The u loads are issued by inline asm in a
// depth-8 rotating pipeline with exact vmcnt(28) waits: the compiler cannot
// sink them (volatile order), so ~700cy of prefetch distance hides L2/HBM
// latency that dominated R3/R4 (465 cy/step with compiler-scheduled loads).
#define GLOAD16(dst, addr, OFFSTR)                                             \
  asm volatile("global_load_dwordx4 %0, %1, off offset:" OFFSTR                \
               : "=&v"(dst)                                                    \
               : "v"(addr))

#define REFILL(J, AREG, O0, O1, O2, O3)                                        \
  GLOAD16(B[J][0], AREG, O0);                                                  \
  GLOAD16(B[J][1], AREG, O1);                                                  \
  GLOAD16(B[J][2], AREG, O2);                                                  \
  GLOAD16(B[J][3], AREG, O3)

#define STEPJ(J)                                                               \
  asm volatile("s_waitcnt vmcnt(28)"                                           \
               : "+v"(B[J][0]), "+v"(B[J][1]), "+v"(B[J][2]), "+v"(B[J][3]));  \
  __builtin_amdgcn_sched_barrier(0);                                           \
  do_step(B[J]);

__launch_bounds__(64, 1)
__global__ void hh_qrows(const float* __restrict__ u,
                         unsigned short* __restrict__ Qb) {
  const int l = threadIdx.x;
  const int r = l >> 4;
  const int c = l & 15;
  const int row = blockIdx.x * 4 + r;
  const int col0 = c * 16;

  float q[16];
#pragma unroll
  for (int i = 0; i < 16; ++i) q[i] = (col0 + i == row) ? 1.f : 0.f;

  f32x4 B[8][4];  // all accesses via compile-time indices -> registers

  auto do_step = [&](const f32x4(&a)[4]) {
    float p0 = 0.f, p1 = 0.f, p2 = 0.f, p3 = 0.f;
#pragma unroll
    for (int e = 0; e < 4; ++e) {
      p0 = fmaf(q[e], a[0][e], p0);
      p1 = fmaf(q[4 + e], a[1][e], p1);
      p2 = fmaf(q[8 + e], a[2][e], p2);
      p3 = fmaf(q[12 + e], a[3][e], p3);
    }
    float p = (p0 + p1) + (p2 + p3);
    p = dpp_add<0xB1>(p);   // quad xor1
    p = dpp_add<0x4E>(p);   // quad xor2
    p = dpp_add<0x124>(p);  // row_ror:4
    p = dpp_add<0x128>(p);  // row_ror:8 -> full 16-lane sum, all lanes
#pragma unroll
    for (int k = 0; k < 4; ++k)
#pragma unroll
      for (int e = 0; e < 4; ++e) q[4 * k + e] = fmaf(-p, a[k][e], q[4 * k + e]);
  };

  unsigned long long a0 = (unsigned long long)(u + col0);   // slots 0..3
  unsigned long long a1 = a0 + 4096;                        // slots 4..7

  // prologue: load steps 0..7
  REFILL(0, a0, "0", "16", "32", "48");
  REFILL(1, a0, "1024", "1040", "1056", "1072");
  REFILL(2, a0, "2048", "2064", "2080", "2096");
  REFILL(3, a0, "3072", "3088", "3104", "3120");
  REFILL(4, a1, "0", "16", "32", "48");
  REFILL(5, a1, "1024", "1040", "1056", "1072");
  REFILL(6, a1, "2048", "2064", "2080", "2096");
  REFILL(7, a1, "3072", "3088", "3104", "3120");
  a0 += 8192; a1 += 8192;

  // 33 iters x 8 steps = 264 steps (258 real + 6 zero-row no-ops).
  // Refills reach row 271 (u padded to 272 rows of 1KB).
  for (int t = 0; t < 33; ++t) {
    STEPJ(0); REFILL(0, a0, "0", "16", "32", "48");
    STEPJ(1); REFILL(1, a0, "1024", "1040", "1056", "1072");
    STEPJ(2); REFILL(2, a0, "2048", "2064", "2080", "2096");
    STEPJ(3); REFILL(3, a0, "3072", "3088", "3104", "3120");
    STEPJ(4); REFILL(4, a1, "0", "16", "32", "48");
    STEPJ(5); REFILL(5, a1, "1024", "1040", "1056", "1072");
    STEPJ(6); REFILL(6, a1, "2048", "2064", "2080", "2096");
    STEPJ(7); REFILL(7, a1, "3072", "3088", "3104", "3120");
    a0 += 8192; a1 += 8192;
  }

  asm volatile("s_waitcnt vmcnt(0)");  // drain dangling refills before endpgm
#pragma unroll
  for (int i = 0; i < 16; ++i) Qb[row * 256 + col0 + i] = f2bf_rne(q[i]);
}

// ---------------- Phase 3: GEMM --------------------------------------------
// C[M=65536][256] = A[M][K=256](f32, cvt->bf16) * B[N=256][K=256](bf16, BT)
// Block: BM=128, BN=256 (full N -> x read exactly once), BK=32, 512 thr (8 waves).
// Wave grid 2x4; per-wave 64x64 = 4x4 frags of 16x16x32.
// LDS 64KB: A dbuf [128][32] f32 @0/16K, B dbuf [256][32] bf16 @32K/48K.
// XOR-swizzled staging (swizzle applied to the GLOBAL source address, LDS dest
// linear as required by global_load_lds) to avoid bank conflicts on ds_read.
__launch_bounds__(512)
__global__ void hh_gemm(const float* __restrict__ X,
                        const unsigned short* __restrict__ Qb,
                        float* __restrict__ Y) {
  __shared__ __align__(128) char lds[65536];
  const int tid = threadIdx.x;
  const int lane = tid & 63;
  const int wid = tid >> 6;
  const int wm = wid >> 2;  // 0..1
  const int wn = wid & 3;   // 0..3
  const int fr = lane & 15; // fragment row (A-row / B-col)
  const int fg = lane >> 4; // k-group
  const long bm0 = (long)blockIdx.x * 128;

  auto stage = [&](int buf, int kt) {
#pragma unroll
    for (int r2 = 0; r2 < 2; ++r2) {
      int slot = r2 * 512 + tid;
      int row = slot >> 3, seg = slot & 7;
      int ps = seg ^ (row & 7);
      GLOAD_LDS16(X + (bm0 + row) * 256 + kt * 32 + ps * 4,
                  lds + buf * 16384 + slot * 16);
    }
#pragma unroll
    for (int r2 = 0; r2 < 2; ++r2) {
      int slot = r2 * 512 + tid;
      int row = slot >> 2, seg = slot & 3;
      int ps = seg ^ (row & 3);
      GLOAD_LDS16(Qb + row * 256 + kt * 32 + ps * 8,
                  lds + 32768 + buf * 16384 + slot * 16);
    }
  };

  f32x4 acc[4][4];
#pragma unroll
  for (int m = 0; m < 4; ++m)
#pragma unroll
    for (int n = 0; n < 4; ++n) acc[m][n] = (f32x4){0.f, 0.f, 0.f, 0.f};

  stage(0, 0);
  __syncthreads();

  for (int kt = 0; kt < 8; ++kt) {
    const int cur = kt & 1;
    if (kt < 7) stage(cur ^ 1, kt + 1);

    bf16x8 aF[4], bF[4];
#pragma unroll
    for (int m = 0; m < 4; ++m) {
      int row = wm * 64 + m * 16 + fr;  // 0..127
      int s0 = (2 * fg) ^ (row & 7);
      int s1 = (2 * fg + 1) ^ (row & 7);
      const f32x4 x0 = *(const f32x4*)(lds + cur * 16384 + row * 128 + s0 * 16);
      const f32x4 x1 = *(const f32x4*)(lds + cur * 16384 + row * 128 + s1 * 16);
      bf16x8 t;
      t[0] = (short)f2bf_rne(x0[0]);
      t[1] = (short)f2bf_rne(x0[1]);
      t[2] = (short)f2bf_rne(x0[2]);
      t[3] = (short)f2bf_rne(x0[3]);
      t[4] = (short)f2bf_rne(x1[0]);
      t[5] = (short)f2bf_rne(x1[1]);
      t[6] = (short)f2bf_rne(x1[2]);
      t[7] = (short)f2bf_rne(x1[3]);
      aF[m] = t;
    }
#pragma unroll
    for (int n = 0; n < 4; ++n) {
      int row = wn * 64 + n * 16 + fr;  // 0..255
      int ps = fg ^ (row & 3);
      bF[n] = *(const bf16x8*)(lds + 32768 + cur * 16384 + row * 64 + ps * 16);
    }
#pragma unroll
    for (int m = 0; m < 4; ++m)
#pragma unroll
      for (int n = 0; n < 4; ++n)
        acc[m][n] =
            __builtin_amdgcn_mfma_f32_16x16x32_bf16(aF[m], bF[n], acc[m][n], 0, 0, 0);
    __syncthreads();
  }

  // Epilogue: C/D layout col = lane&15, row = (lane>>4)*4 + reg
#pragma unroll
  for (int m = 0; m < 4; ++m)
#pragma unroll
    for (int n = 0; n < 4; ++n)
#pragma unroll
      for (int r = 0; r < 4; ++r) {
        long grow = bm0 + wm * 64 + m * 16 + fg * 4 + r;
        int gcol = wn * 64 + n * 16 + fr;
        Y[grow * 256 + gcol] = acc[m][n][r];
      }
}

// ---------------------------------------------------------------------------
extern "C" void kernel_launch(void* const* d_in, const int* in_sizes, int n_in,
                              void* d_out, int out_size, void* d_ws, size_t ws_size,
                              hipStream_t stream) {
  const float* x = (const float*)d_in[0];      // [65536][256] f32
  const float* vecs = (const float*)d_in[1];   // [258][256] f32
  float* y = (float*)d_out;                    // [65536][256] f32

  float* u = (float*)d_ws;                                        // 272x256 f32
  unsigned short* Qb = (unsigned short*)((char*)d_ws + 278528);   // 256x256 bf16

  hh_scale<<<272, 64, 0, stream>>>(vecs, u);
  hh_qrows<<<64, 64, 0, stream>>>(u, Qb);
  hh_gemm<<<512, 512, 0, stream>>>(x, Qb, y);
}

// Round 8
// 65.809 us; speedup vs baseline: 1.2310x; 1.0075x over previous
//
#include <hip/hip_runtime.h>

// ---------------------------------------------------------------------------
// y = x @ Q^T where Q = H_0 H_1 ... H_{N-1}, H_n = I - 2 v_n v_n^T/(v_n.v_n+eps)
// S=256, N=258, B=65536.
// Phase 1: u_n = sqrt(2/(v_n.v_n+eps)) * v_n  (rows 258..271 zeroed: no-op pad)
// Phase 2: 8 PARALLEL chunk cascades Q_c = H_{33c}..H_{33c+32} (33-step chains,
//          512 blocks, plain C++ -- R3-verified step pattern, no inline asm).
// Phase 2b: merge tree (fp32 256^3 GEMMs): P=QcQc, R=PP, Q=RR -> bf16 Qb.
// Phase 3: GEMM y[b][j] = sum_k x[b][k] Qb[j][k]  (BT layout, bf16 MFMA)
//
// Scratch: d_ws holds u (272KB) + Qb (128KB) = R5-proven 410KB footprint.
// Qc/P/R (3.5MB) live in d_out (64MB), each region written before read every
// call and fully overwritten by hh_gemm afterwards.
// ---------------------------------------------------------------------------

#define GLOAD_LDS16(g, l)                                                      \
  __builtin_amdgcn_global_load_lds(                                            \
      (const __attribute__((address_space(1))) void*)(g),                      \
      (__attribute__((address_space(3))) void*)(l), 16, 0, 0)

typedef __attribute__((ext_vector_type(8))) short bf16x8;
typedef __attribute__((ext_vector_type(4))) float f32x4;

__device__ __forceinline__ unsigned short f2bf_rne(float f) {
  unsigned u = __builtin_bit_cast(unsigned, f);
  return (unsigned short)((u + 0x7fffu + ((u >> 16) & 1u)) >> 16);
}

// DPP-shuffled add: v + dpp(v). CTRL: 0xB1=quad xor1, 0x4E=quad xor2,
// 0x124=row_ror:4, 0x128=row_ror:8. Pure VALU latency, no LDS.
template <int CTRL>
__device__ __forceinline__ float dpp_add(float v) {
  int t = __builtin_amdgcn_update_dpp(0, __builtin_bit_cast(int, v), CTRL, 0xF,
                                      0xF, true);
  return v + __builtin_bit_cast(float, t);
}

// ---------------- Phase 1: scaled vectors u --------------------------------
// 272 blocks x 64 lanes. Lane l owns 4 contiguous floats (float4 at l*16B).
// n<258: u_n = v_n * sqrt(2/(v.v+1e-16)); n>=258: zeros (pad rows = no-op).
__global__ void hh_scale(const float* __restrict__ vecs, float* __restrict__ u) {
  const int n = blockIdx.x;   // 0..271
  const int l = threadIdx.x;  // 0..63
  float4* uo = (float4*)(u + (long)n * 256) + l;
  if (n >= 258) {
    *uo = make_float4(0.f, 0.f, 0.f, 0.f);
    return;
  }
  const float4 v = *((const float4*)(vecs + (long)n * 256) + l);
  float p = v.x * v.x + v.y * v.y + v.z * v.z + v.w * v.w;
#pragma unroll
  for (int off = 32; off; off >>= 1) p += __shfl_xor(p, off);
  const float s = sqrtf(2.0f / (p + 1e-16f));
  *uo = make_float4(v.x * s, v.y * s, v.z * s, v.w * s);
}

// ---------------- Phase 2: chunked Q rows (plain C++) ----------------------
// 512 blocks x 64 threads (1 wave). Block = (chunk c = bx>>6, rowgroup bx&63).
// Lane l: row-in-group r=l>>4, col c16=l&15 (16 contiguous cols per lane).
// Each block computes 4 rows of Q_c = H_{33c}..H_{33c+32} (33 steps).
// Plain C++ double-buffer prefetch; with only 33 steps and 512 blocks the
// exposed load latency (~400cy/step worst case) totals ~5us -- acceptable.
__launch_bounds__(64, 1)
__global__ void hh_qchunk(const float* __restrict__ u,
                          float* __restrict__ Qc) {
  const int l = threadIdx.x;
  const int chunk = blockIdx.x >> 6;   // 0..7
  const int rg = blockIdx.x & 63;      // 0..63
  const int r = l >> 4;
  const int c = l & 15;
  const int row = rg * 4 + r;
  const int col0 = c * 16;

  float q[16];
#pragma unroll
  for (int i = 0; i < 16; ++i) q[i] = (col0 + i == row) ? 1.f : 0.f;

  // chunk c uses u rows 33c..33c+32; prefetch may touch row 33c+33 <= 264 < 272
  const float* ub = u + (long)chunk * 33 * 256 + col0;

  auto load16 = [&](float(&d)[16], int n) {
    const float4* v = (const float4*)(ub + (long)n * 256);
#pragma unroll
    for (int i = 0; i < 4; ++i) {
      float4 t = v[i];
      d[4 * i] = t.x; d[4 * i + 1] = t.y; d[4 * i + 2] = t.z; d[4 * i + 3] = t.w;
    }
  };

  auto step = [&](const float(&a)[16]) {
    float p0 = 0.f, p1 = 0.f, p2 = 0.f, p3 = 0.f;
#pragma unroll
    for (int e = 0; e < 4; ++e) {
      p0 = fmaf(q[e], a[e], p0);
      p1 = fmaf(q[4 + e], a[4 + e], p1);
      p2 = fmaf(q[8 + e], a[8 + e], p2);
      p3 = fmaf(q[12 + e], a[12 + e], p3);
    }
    float p = (p0 + p1) + (p2 + p3);
    p = dpp_add<0xB1>(p);   // quad xor1
    p = dpp_add<0x4E>(p);   // quad xor2
    p = dpp_add<0x124>(p);  // row_ror:4
    p = dpp_add<0x128>(p);  // row_ror:8 -> full 16-lane sum, all lanes
#pragma unroll
    for (int k = 0; k < 16; ++k) q[k] = fmaf(-p, a[k], q[k]);
  };

  float A0[16], A1[16];
  load16(A0, 0);
  load16(A1, 1);
  for (int n = 0; n < 32; n += 2) {
    step(A0);
    load16(A0, n + 2);        // n+2 <= 32 (chunk rows)
    step(A1);
    load16(A1, n + 3);        // n+3 <= 33: row 33c+33 <= 264 < 272, harmless
  }
  step(A0);  // step 32

  float4* out = (float4*)(Qc + (long)chunk * 65536 + row * 256 + col0);
#pragma unroll
  for (int i = 0; i < 4; ++i)
    out[i] = make_float4(q[4 * i], q[4 * i + 1], q[4 * i + 2], q[4 * i + 3]);
}

// ---------------- Phase 2b: fp32 merge GEMM --------------------------------
// C_b = A_b * B_b for consecutive 256x256 fp32 pairs in `in`
// (A=in+b*2*65536, B=A+65536). Grid = batch*64 blocks, 256 thr.
// Block computes a 32x32 tile; thread 2x2; K staged via LDS in 64-wide tiles.
// to_bf16: last level writes bf16 Qb instead of fp32.
__launch_bounds__(256)
__global__ void hh_mm(const float* __restrict__ in, float* __restrict__ out,
                      unsigned short* __restrict__ outb, int to_bf16) {
  const int b = blockIdx.x >> 6;
  const int t = blockIdx.x & 63;
  const int ti = (t >> 3) * 32, tj = (t & 7) * 32;
  const int tid = threadIdx.x;
  const int tx = tid & 15, ty = tid >> 4;
  const float* A = in + (long)b * 2 * 65536;
  const float* Bm = A + 65536;

  __shared__ float As[32][68];  // pad 68: row-stride bank-offset for col reads
  __shared__ float Bs[64][36];  // pad 36 keeps float4 alignment

  float acc00 = 0.f, acc01 = 0.f, acc10 = 0.f, acc11 = 0.f;

  for (int k0 = 0; k0 < 256; k0 += 64) {
#pragma unroll
    for (int u0 = 0; u0 < 2048; u0 += 1024) {
      int idx = u0 + tid * 4;
      int rr = idx >> 6, cc = idx & 63;
      *(float4*)&As[rr][cc] = *(const float4*)&A[(ti + rr) * 256 + k0 + cc];
      int kk = idx >> 5, jj = idx & 31;
      *(float4*)&Bs[kk][jj] = *(const float4*)&Bm[(k0 + kk) * 256 + tj + jj];
    }
    __syncthreads();
#pragma unroll 8
    for (int kk = 0; kk < 64; ++kk) {
      float a0 = As[2 * ty][kk], a1 = As[2 * ty + 1][kk];
      float b0 = Bs[kk][2 * tx], b1 = Bs[kk][2 * tx + 1];
      acc00 = fmaf(a0, b0, acc00);
      acc01 = fmaf(a0, b1, acc01);
      acc10 = fmaf(a1, b0, acc10);
      acc11 = fmaf(a1, b1, acc11);
    }
    __syncthreads();
  }

  const int gi = ti + 2 * ty, gj = tj + 2 * tx;
  if (to_bf16) {
    unsigned short* o = outb + (long)b * 65536;
    o[gi * 256 + gj] = f2bf_rne(acc00);
    o[gi * 256 + gj + 1] = f2bf_rne(acc01);
    o[(gi + 1) * 256 + gj] = f2bf_rne(acc10);
    o[(gi + 1) * 256 + gj + 1] = f2bf_rne(acc11);
  } else {
    float* o = out + (long)b * 65536;
    o[gi * 256 + gj] = acc00;
    o[gi * 256 + gj + 1] = acc01;
    o[(gi + 1) * 256 + gj] = acc10;
    o[(gi + 1) * 256 + gj + 1] = acc11;
  }
}

// ---------------- Phase 3: GEMM --------------------------------------------
// C[M=65536][256] = A[M][K=256](f32, cvt->bf16) * B[N=256][K=256](bf16, BT)
// Block: BM=128, BN=256 (full N -> x read exactly once), BK=32, 512 thr (8 waves).
// Wave grid 2x4; per-wave 64x64 = 4x4 frags of 16x16x32.
// LDS 64KB: A dbuf [128][32] f32 @0/16K, B dbuf [256][32] bf16 @32K/48K.
// XOR-swizzled staging (swizzle applied to the GLOBAL source address, LDS dest
// linear as required by global_load_lds) to avoid bank conflicts on ds_read.
__launch_bounds__(512)
__global__ void hh_gemm(const float* __restrict__ X,
                        const unsigned short* __restrict__ Qb,
                        float* __restrict__ Y) {
  __shared__ __align__(128) char lds[65536];
  const int tid = threadIdx.x;
  const int lane = tid & 63;
  const int wid = tid >> 6;
  const int wm = wid >> 2;  // 0..1
  const int wn = wid & 3;   // 0..3
  const int fr = lane & 15; // fragment row (A-row / B-col)
  const int fg = lane >> 4; // k-group
  const long bm0 = (long)blockIdx.x * 128;

  auto stage = [&](int buf, int kt) {
#pragma unroll
    for (int r2 = 0; r2 < 2; ++r2) {
      int slot = r2 * 512 + tid;
      int row = slot >> 3, seg = slot & 7;
      int ps = seg ^ (row & 7);
      GLOAD_LDS16(X + (bm0 + row) * 256 + kt * 32 + ps * 4,
                  lds + buf * 16384 + slot * 16);
    }
#pragma unroll
    for (int r2 = 0; r2 < 2; ++r2) {
      int slot = r2 * 512 + tid;
      int row = slot >> 2, seg = slot & 3;
      int ps = seg ^ (row & 3);
      GLOAD_LDS16(Qb + row * 256 + kt * 32 + ps * 8,
                  lds + 32768 + buf * 16384 + slot * 16);
    }
  };

  f32x4 acc[4][4];
#pragma unroll
  for (int m = 0; m < 4; ++m)
#pragma unroll
    for (int n = 0; n < 4; ++n) acc[m][n] = (f32x4){0.f, 0.f, 0.f, 0.f};

  stage(0, 0);
  __syncthreads();

  for (int kt = 0; kt < 8; ++kt) {
    const int cur = kt & 1;
    if (kt < 7) stage(cur ^ 1, kt + 1);

    bf16x8 aF[4], bF[4];
#pragma unroll
    for (int m = 0; m < 4; ++m) {
      int row = wm * 64 + m * 16 + fr;  // 0..127
      int s0 = (2 * fg) ^ (row & 7);
      int s1 = (2 * fg + 1) ^ (row & 7);
      const f32x4 x0 = *(const f32x4*)(lds + cur * 16384 + row * 128 + s0 * 16);
      const f32x4 x1 = *(const f32x4*)(lds + cur * 16384 + row * 128 + s1 * 16);
      bf16x8 t;
      t[0] = (short)f2bf_rne(x0[0]);
      t[1] = (short)f2bf_rne(x0[1]);
      t[2] = (short)f2bf_rne(x0[2]);
      t[3] = (short)f2bf_rne(x0[3]);
      t[4] = (short)f2bf_rne(x1[0]);
      t[5] = (short)f2bf_rne(x1[1]);
      t[6] = (short)f2bf_rne(x1[2]);
      t[7] = (short)f2bf_rne(x1[3]);
      aF[m] = t;
    }
#pragma unroll
    for (int n = 0; n < 4; ++n) {
      int row = wn * 64 + n * 16 + fr;  // 0..255
      int ps = fg ^ (row & 3);
      bF[n] = *(const bf16x8*)(lds + 32768 + cur * 16384 + row * 64 + ps * 16);
    }
#pragma unroll
    for (int m = 0; m < 4; ++m)
#pragma unroll
      for (int n = 0; n < 4; ++n)
        acc[m][n] =
            __builtin_amdgcn_mfma_f32_16x16x32_bf16(aF[m], bF[n], acc[m][n], 0, 0, 0);
    __syncthreads();
  }

  // Epilogue: C/D layout col = lane&15, row = (lane>>4)*4 + reg
#pragma unroll
  for (int m = 0; m < 4; ++m)
#pragma unroll
    for (int n = 0; n < 4; ++n)
#pragma unroll
      for (int r = 0; r < 4; ++r) {
        long grow = bm0 + wm * 64 + m * 16 + fg * 4 + r;
        int gcol = wn * 64 + n * 16 + fr;
        Y[grow * 256 + gcol] = acc[m][n][r];
      }
}

// ---------------------------------------------------------------------------
extern "C" void kernel_launch(void* const* d_in, const int* in_sizes, int n_in,
                              void* d_out, int out_size, void* d_ws, size_t ws_size,
                              hipStream_t stream) {
  const float* x = (const float*)d_in[0];      // [65536][256] f32
  const float* vecs = (const float*)d_in[1];   // [258][256] f32
  float* y = (float*)d_out;                    // [65536][256] f32

  // d_ws: only the small buffers (R5-proven 410KB footprint)
  char* ws = (char*)d_ws;
  float* u = (float*)ws;                                // 272x256 f32 (278528 B)
  unsigned short* Qb = (unsigned short*)(ws + 278528);  // 256x256 bf16 (131072 B)

  // Large intermediates live in d_out scratch space (64MB; all regions are
  // dead before hh_gemm overwrites the full buffer).
  char* ob = (char*)d_out;
  float* Qc = (float*)(ob);                 // 8 x 256x256 f32 (2 MB)
  float* P = (float*)(ob + 2097152);        // 4 x 256x256 f32 (1 MB)
  float* R = (float*)(ob + 3145728);        // 2 x 256x256 f32 (512 KB)

  hh_scale<<<272, 64, 0, stream>>>(vecs, u);
  hh_qchunk<<<512, 64, 0, stream>>>(u, Qc);
  hh_mm<<<256, 256, 0, stream>>>(Qc, P, nullptr, 0);   // 4 pair-products
  hh_mm<<<128, 256, 0, stream>>>(P, R, nullptr, 0);    // 2 pair-products
  hh_mm<<<64, 256, 0, stream>>>(R, nullptr, Qb, 1);    // final -> bf16 Qb
  hh_gemm<<<512, 512, 0, stream>>>(x, Qb, y);
}